// Round 12
// baseline (226.935 us; speedup 1.0000x reference)
//
#include <hip/hip_runtime.h>

typedef unsigned short u16t;
typedef __bf16 bf16x8 __attribute__((ext_vector_type(8)));
typedef float  f32x4  __attribute__((ext_vector_type(4)));
typedef float  f32x16 __attribute__((ext_vector_type(16)));
typedef unsigned u32x2 __attribute__((ext_vector_type(2)));
typedef unsigned u32x4 __attribute__((ext_vector_type(4)));

#define DEV __device__ __forceinline__

DEV u16t f32_to_bf16(float f) {
    unsigned u = __float_as_uint(f);
    unsigned r = (u + 0x7FFFu + ((u >> 16) & 1u)) >> 16;   // RNE
    return (u16t)r;
}
DEV float bf16_to_f32(u16t u) { return __uint_as_float((unsigned)u << 16); }

DEV unsigned cvt_pk_bf16(float lo, float hi) {
    unsigned r;
    asm("v_cvt_pk_bf16_f32 %0, %1, %2" : "=v"(r) : "v"(lo), "v"(hi));
    return r;
}

DEV float gelu_exact(float x) {
    return 0.5f * x * (1.0f + erff(x * 0.70710678118654752f));
}

DEV void glds16(const void* g, void* l) {
    __builtin_amdgcn_global_load_lds(
        (const __attribute__((address_space(1))) void*)g,
        (__attribute__((address_space(3))) void*)l, 16, 0, 0);
}

#define SCHED_FENCE() __builtin_amdgcn_sched_barrier(0)

// counted-wait + raw barrier pair (never drain in-flight prefetch)
#define WAITN_BARRIER(N)                                          \
    asm volatile("s_waitcnt vmcnt(" #N ")" ::: "memory");         \
    SCHED_FENCE();                                                \
    __builtin_amdgcn_s_barrier();                                 \
    SCHED_FENCE();

#define PLAIN_BARRIER()                                           \
    SCHED_FENCE();                                                \
    __builtin_amdgcn_s_barrier();                                 \
    SCHED_FENCE();

// ---------------------------------------------------------------- LayerNorm
__global__ __launch_bounds__(256)
void ln_kernel(const float* __restrict__ x, const float* __restrict__ g,
               const float* __restrict__ b, u16t* __restrict__ out)
{
    const int row = blockIdx.x;
    const int t = threadIdx.x;
    const float* xr = x + (size_t)row * 768;
    float v0 = xr[t], v1 = xr[t + 256], v2 = xr[t + 512];
    float s = v0 + v1 + v2;
    float s2 = v0 * v0 + v1 * v1 + v2 * v2;
#pragma unroll
    for (int off = 32; off > 0; off >>= 1) {
        s  += __shfl_xor(s, off);
        s2 += __shfl_xor(s2, off);
    }
    __shared__ float sm[8];
    const int w = t >> 6;
    if ((t & 63) == 0) { sm[w] = s; sm[4 + w] = s2; }
    __syncthreads();
    s  = sm[0] + sm[1] + sm[2] + sm[3];
    s2 = sm[4] + sm[5] + sm[6] + sm[7];
    const float mu  = s * (1.0f / 768.0f);
    const float var = fmaxf(s2 * (1.0f / 768.0f) - mu * mu, 0.0f);
    const float rst = rsqrtf(var + 1e-5f);
    u16t* o = out + (size_t)row * 768;
    o[t]       = f32_to_bf16((v0 - mu) * rst * g[t]       + b[t]);
    o[t + 256] = f32_to_bf16((v1 - mu) * rst * g[t + 256] + b[t + 256]);
    o[t + 512] = f32_to_bf16((v2 - mu) * rst * g[t + 512] + b[t + 512]);
}

// ----------------------------------- all 4 weight transposes in one launch
__global__ __launch_bounds__(256)
void transpose_all(const float* __restrict__ Wqkv, const float* __restrict__ Wout,
                   const float* __restrict__ W1, const float* __restrict__ W2,
                   u16t* __restrict__ WqkvT, u16t* __restrict__ WoutT,
                   u16t* __restrict__ W1T, u16t* __restrict__ W2T)
{
    int b = blockIdx.x;
    const float* in; u16t* out; int R, C, cx, ry;
    if (b < 432)       { in = Wqkv; out = WqkvT; R = 768;  C = 2304; cx = b % 36; ry = b / 36; }
    else if (b < 576)  { b -= 432;  in = Wout; out = WoutT; R = 768;  C = 768;  cx = b % 12; ry = b / 12; }
    else if (b < 1152) { b -= 576;  in = W1;   out = W1T;   R = 768;  C = 3072; cx = b % 48; ry = b / 48; }
    else               { b -= 1152; in = W2;   out = W2T;   R = 3072; C = 768;  cx = b % 12; ry = b / 12; }
    __shared__ float tile[64][65];
    const int c0 = cx * 64, r0 = ry * 64;
    const int t = threadIdx.x;
#pragma unroll
    for (int j = 0; j < 16; ++j) {
        const int idx = j * 256 + t;
        const int rl = idx >> 6, cl = idx & 63;
        tile[rl][cl] = in[(size_t)(r0 + rl) * C + c0 + cl];
    }
    __syncthreads();
#pragma unroll
    for (int j = 0; j < 16; ++j) {
        const int idx = j * 256 + t;
        const int cl = idx >> 6, rl = idx & 63;
        out[(size_t)(c0 + cl) * R + r0 + rl] = f32_to_bf16(tile[rl][cl]);
    }
}

// ------------------------------------------------------------------- GEMM
// C[M,N] = A[M,K] * BT[N,K]^T, bf16 in, TM x 128 tile (TM=128 or 64), BK=64,
// double-buffered LDS (128B rows, slot-XOR s^(row&7) both sides), counted
// vmcnt + raw barriers (no drains). 32 (TM=128) or 16 (TM=64) MFMA per
// barrier pair.
// MODE 0: f32. MODE 1: +res(+bias) f32. MODE 2: gelu(acc+bias) bf16.
// MODE 3: qkv epilogue -> Q,K [B*H,N,64] bf16 + VT [B*H,64,N] (TM=128 only).
template <int MODE, int TM>
__global__ __launch_bounds__(256)
void gemm_kernel(const u16t* __restrict__ A, const u16t* __restrict__ BT,
                 float* __restrict__ Cf, u16t* __restrict__ Cb,
                 const float* __restrict__ bias, const float* __restrict__ res,
                 u16t* __restrict__ Qo, u16t* __restrict__ Ko,
                 u16t* __restrict__ VTo,
                 int M, int Nn, int K)
{
    constexpr int MI = TM / 32;          // acc row-frags per wave (4 or 2)
    constexpr int ABYTES = TM * 128;     // A tile bytes per buffer
    constexpr int BUFB = ABYTES + 16384; // buffer stride (A + B[128][128B])
    __shared__ __align__(16) char gsm[2 * BUFB];
    const int t = threadIdx.x;
    const int w = t >> 6, lane = t & 63;
    const int l16 = lane & 15, lhi = lane >> 4;
    const int wr = w >> 1, wc = w & 1;
    const int m0 = blockIdx.x * TM, n0 = blockIdx.y * 128;

    const f32x4 fz = {0.f, 0.f, 0.f, 0.f};
    f32x4 acc[MI][4];
#pragma unroll
    for (int i = 0; i < MI; ++i)
#pragma unroll
        for (int j = 0; j < 4; ++j) acc[i][j] = fz;

    // staging: rows of 128B (64 bf16). Round i covers 32 rows; thread t ->
    // row i*32 + (t>>3), dest slot t&7 (linear), src slot (t&7)^((t>>3)&7).
    const int rbase = t >> 3;                       // 0..31
    const int ssrc = ((t & 7) ^ (rbase & 7)) * 16;  // pre-swizzled src slot

    auto stage = [&](int bufb, int kt) {
#pragma unroll
        for (int i = 0; i < TM / 32; ++i) {
            const int row = i * 32 + rbase;
            glds16((const char*)A + ((size_t)(m0 + row) * K + kt) * 2 + ssrc,
                   gsm + bufb + i * 4096 + t * 16);
        }
#pragma unroll
        for (int i = 0; i < 4; ++i) {
            const int row = i * 32 + rbase;
            glds16((const char*)BT + ((size_t)(n0 + row) * K + kt) * 2 + ssrc,
                   gsm + bufb + ABYTES + i * 4096 + t * 16);
        }
    };

    auto body = [&](int bufb) {
        const char* Ab = gsm + bufb;
        const char* Bb = gsm + bufb + ABYTES;
#pragma unroll
        for (int ks = 0; ks < 2; ++ks) {        // kk = 0, 32
            const int wsl = lhi + 4 * ks;
            bf16x8 af[MI], bfv[4];
#pragma unroll
            for (int i = 0; i < MI; ++i) {
                const int row = 16 * MI * wr + 16 * i + l16;
                af[i] = *reinterpret_cast<const bf16x8*>(
                    Ab + row * 128 + ((wsl ^ (row & 7)) << 4));
            }
#pragma unroll
            for (int j = 0; j < 4; ++j) {
                const int row = 64 * wc + 16 * j + l16;
                bfv[j] = *reinterpret_cast<const bf16x8*>(
                    Bb + row * 128 + ((wsl ^ (row & 7)) << 4));
            }
#pragma unroll
            for (int i = 0; i < MI; ++i)
#pragma unroll
                for (int j = 0; j < 4; ++j)
                    acc[i][j] = __builtin_amdgcn_mfma_f32_16x16x32_bf16(
                        af[i], bfv[j], acc[i][j], 0, 0, 0);
        }
    };

    stage(0, 0);
    int bufb = 0;
    for (int kt = 0; kt + 64 < K; kt += 64) {
        stage(bufb ^ BUFB, kt + 64);
        if constexpr (TM == 128) { WAITN_BARRIER(8) }
        else                     { WAITN_BARRIER(6) }
        body(bufb);
        PLAIN_BARRIER()
        bufb ^= BUFB;
    }
    WAITN_BARRIER(0)
    body(bufb);

    const int rb = m0 + 16 * MI * wr + 4 * lhi;
    const int cb = n0 + 64 * wc + l16;

    if constexpr (MODE == 3) {
        const int qi = n0 / 768;
        const int b = rb >> 11;
        const int nn0 = rb & 2047;
#pragma unroll
        for (int j = 0; j < 4; ++j) {
            const int c = cb - qi * 768 + 16 * j;   // 0..767
            const int h = c >> 6, d = c & 63;
            if (qi < 2) {
                u16t* dst = (qi == 0) ? Qo : Ko;
                const size_t base = ((size_t)(b * 12 + h) * 2048 + nn0) * 64 + d;
#pragma unroll
                for (int i = 0; i < MI; ++i)
#pragma unroll
                    for (int r = 0; r < 4; ++r)
                        dst[base + (size_t)(16 * i + r) * 64] =
                            f32_to_bf16(acc[i][j][r]);
            } else {
                u16t* dst = VTo + ((size_t)(b * 12 + h) * 64 + d) * 2048 + nn0;
#pragma unroll
                for (int i = 0; i < MI; ++i) {
                    u32x2 pr;
                    pr[0] = cvt_pk_bf16(acc[i][j][0], acc[i][j][1]);
                    pr[1] = cvt_pk_bf16(acc[i][j][2], acc[i][j][3]);
                    *reinterpret_cast<u32x2*>(dst + 16 * i) = pr;
                }
            }
        }
        return;
    }

#pragma unroll
    for (int i = 0; i < MI; ++i) {
#pragma unroll
        for (int j = 0; j < 4; ++j) {
#pragma unroll
            for (int r = 0; r < 4; ++r) {
                const int row = rb + 16 * i + r;
                const int col = cb + 16 * j;
                float v = acc[i][j][r];
                if (MODE == 0) {
                    Cf[(size_t)row * Nn + col] = v;
                } else if (MODE == 1) {
                    v += res[(size_t)row * Nn + col];
                    if (bias) v += bias[col];
                    Cf[(size_t)row * Nn + col] = v;
                } else if (MODE == 2) {
                    v = gelu_exact(v + bias[col]);
                    Cb[(size_t)row * Nn + col] = f32_to_bf16(v);
                }
            }
        }
    }
}

// ------------------------------------------------------- flash attention
// R9-proven config: swapped-operand 32x32 MFMA, 2-batch fused (bias staged
// once, shared), all streams via glds into a full double buffer (64KB ->
// 2 blocks/CU), counted vmcnt(8)+barrier. Max-free softmax, 4-way k-split.
// grid (16 qblk, 12 h, 4 ks), block 256.
__global__ __launch_bounds__(256, 2)
void attn_kernel(const u16t* __restrict__ Q, const u16t* __restrict__ K,
                 const u16t* __restrict__ VT, const float* __restrict__ bias,
                 u16t* __restrict__ Opart, float* __restrict__ Lpart)
{
    const int SEQ = 2048;
    const int h = blockIdx.y;
    const int ks = blockIdx.z;
    const int t = threadIdx.x;
    const int w = t >> 6, lane = t & 63;
    const int l32 = lane & 31, hi = lane >> 5;
    const int q = blockIdx.x * 128 + w * 32 + l32;
    const int bh0 = h, bh1 = 12 + h;

    // per 32KB buffer: [0,16K) bias [128q][128B=32k f32] swz row&7
    //   [16K) K0 [32k][128B] swz row&7 | [20K) K1 | [24K) V0 [64d][64B]
    //   swz (row>>1)&3 | [28K) V1.  Two buffers (64KB total).
    __shared__ __align__(16) char smem[65536];

    const u16t* qp0 = Q + ((size_t)bh0 * SEQ + q) * 64 + 8 * hi;
    const u16t* qp1 = Q + ((size_t)bh1 * SEQ + q) * 64 + 8 * hi;
    bf16x8 qf0[4], qf1[4];
#pragma unroll
    for (int dseg = 0; dseg < 4; ++dseg) {
        qf0[dseg] = *reinterpret_cast<const bf16x8*>(qp0 + dseg * 16);
        qf1[dseg] = *reinterpret_cast<const bf16x8*>(qp1 + dseg * 16);
    }

    const char* kg0 = (const char*)K + (size_t)bh0 * SEQ * 128;    // 128B rows
    const char* kg1 = (const char*)K + (size_t)bh1 * SEQ * 128;
    const char* vg0 = (const char*)VT + (size_t)bh0 * 64 * 4096;   // 4KB rows
    const char* vg1 = (const char*)VT + (size_t)bh1 * 64 * 4096;
    const char* bg = (const char*)bias +
                     ((size_t)h * SEQ + blockIdx.x * 128) * 8192;  // 8KB rows

    const int srow8 = lane >> 3;                        // 0..7
    const int sslotK = ((lane & 7) ^ srow8) * 16;       // 128B-row swizzle
    const int vrow  = w * 16 + (lane >> 2);             // 0..63
    const int sslotV = ((lane & 3) ^ ((vrow >> 1) & 3)) * 16;

    auto stage_all = [&](int bb, int k0) {              // 8 glds per wave
#pragma unroll
        for (int i = 0; i < 4; ++i) {
            const int row = 32 * w + 8 * i + srow8;
            glds16(bg + (size_t)row * 8192 + (size_t)k0 * 4 + sslotK,
                   smem + bb + 4096 * w + i * 1024);
        }
        glds16(kg0 + (size_t)(k0 + 8 * w + srow8) * 128 + sslotK,
               smem + bb + 16384 + w * 1024);
        glds16(kg1 + (size_t)(k0 + 8 * w + srow8) * 128 + sslotK,
               smem + bb + 20480 + w * 1024);
        glds16(vg0 + (size_t)vrow * 4096 + (size_t)k0 * 2 + sslotV,
               smem + bb + 24576 + w * 1024);
        glds16(vg1 + (size_t)vrow * 4096 + (size_t)k0 * 2 + sslotV,
               smem + bb + 28672 + w * 1024);
    };

    const int rsw = l32 & 7;
    int boff[4], koff[4];
#pragma unroll
    for (int g = 0; g < 4; ++g)
        boff[g] = (32 * w + l32) * 128 + ((((g << 1) + hi) ^ rsw) << 4);
#pragma unroll
    for (int dseg = 0; dseg < 4; ++dseg)
        koff[dseg] = l32 * 128 + ((((dseg << 1) + hi) ^ rsw) << 4);
    const int vr3 = (l32 >> 1) & 3;
    const int voff00 = l32 * 64 + ((hi ^ vr3) << 4);
    const int voff01 = l32 * 64 + (((2 + hi) ^ vr3) << 4);
    const int voff10 = voff00 + 32 * 64;
    const int voff11 = voff01 + 32 * 64;

    f32x16 o00, o01, o10, o11;   // [batch][d-half]
#pragma unroll
    for (int i = 0; i < 16; ++i) { o00[i] = 0.f; o01[i] = 0.f;
                                   o10[i] = 0.f; o11[i] = 0.f; }
    float lsum0 = 0.f, lsum1 = 0.f;

    auto batch_body = [&](const bf16x8 (&qf)[4], int kvbase, int vbase,
                          const f32x4 (&bv)[4], f32x16& oa, f32x16& ob,
                          float& lsum) {
        f32x16 st;
#pragma unroll
        for (int i = 0; i < 16; ++i) st[i] = 0.f;
#pragma unroll
        for (int dseg = 0; dseg < 4; ++dseg) {
            bf16x8 kf = *reinterpret_cast<const bf16x8*>(
                smem + kvbase + koff[dseg]);
            st = __builtin_amdgcn_mfma_f32_32x32x16_bf16(kf, qf[dseg], st, 0, 0, 0);
        }
        unsigned pk[8];
#pragma unroll
        for (int i2 = 0; i2 < 8; ++i2) {
            const int ia = 2 * i2, ib = 2 * i2 + 1;
            const float pa = __expf(st[ia] * 0.125f + bv[ia >> 2][ia & 3]);
            const float pb = __expf(st[ib] * 0.125f + bv[ib >> 2][ib & 3]);
            lsum += pa + pb;
            pk[i2] = cvt_pk_bf16(pa, pb);
        }
        unsigned sx[8];
#pragma unroll
        for (int i2 = 0; i2 < 8; ++i2)
            sx[i2] = (unsigned)__shfl_xor((int)pk[i2], 32);
        union { unsigned u[4]; bf16x8 v; } B0, B1;
        B0.u[0] = hi ? sx[2] : pk[0];
        B0.u[1] = hi ? sx[3] : pk[1];
        B0.u[2] = hi ? pk[2] : sx[0];
        B0.u[3] = hi ? pk[3] : sx[1];
        B1.u[0] = hi ? sx[6] : pk[4];
        B1.u[1] = hi ? sx[7] : pk[5];
        B1.u[2] = hi ? pk[6] : sx[4];
        B1.u[3] = hi ? pk[7] : sx[5];
        bf16x8 v00 = *reinterpret_cast<const bf16x8*>(smem + vbase + voff00);
        bf16x8 v01 = *reinterpret_cast<const bf16x8*>(smem + vbase + voff01);
        bf16x8 v10 = *reinterpret_cast<const bf16x8*>(smem + vbase + voff10);
        bf16x8 v11 = *reinterpret_cast<const bf16x8*>(smem + vbase + voff11);
        oa = __builtin_amdgcn_mfma_f32_32x32x16_bf16(v00, B0.v, oa, 0, 0, 0);
        oa = __builtin_amdgcn_mfma_f32_32x32x16_bf16(v01, B1.v, oa, 0, 0, 0);
        ob = __builtin_amdgcn_mfma_f32_32x32x16_bf16(v10, B0.v, ob, 0, 0, 0);
        ob = __builtin_amdgcn_mfma_f32_32x32x16_bf16(v11, B1.v, ob, 0, 0, 0);
    };

    const int kbeg = ks * 512;

    stage_all(0, kbeg);
    WAITN_BARRIER(0)

    int cur = 0;
    for (int i = 0; i < 16; ++i) {
        const int k0 = kbeg + 32 * i;
        if (i < 15) {
            stage_all(cur ^ 32768, k0 + 32);   // 8 glds: tile i+1
            WAITN_BARRIER(8)                   // retires tile i's 8 glds
        } else {
            WAITN_BARRIER(0)
        }
        {
            f32x4 bv[4];
#pragma unroll
            for (int g = 0; g < 4; ++g)
                bv[g] = *reinterpret_cast<const f32x4*>(smem + cur + boff[g]);
            batch_body(qf0, cur + 16384, cur + 24576, bv, o00, o01, lsum0);
            batch_body(qf1, cur + 20480, cur + 28672, bv, o10, o11, lsum1);
        }
        PLAIN_BARRIER()                        // all waves done reading buf cur
        cur ^= 32768;
    }

    lsum0 += __shfl_xor(lsum0, 32);
    lsum1 += __shfl_xor(lsum1, 32);

#pragma unroll
    for (int beta = 0; beta < 2; ++beta) {
        const int bh = beta ? bh1 : bh0;
        const f32x16& oa = beta ? o10 : o00;
        const f32x16& ob = beta ? o11 : o01;
        const float ls = beta ? lsum1 : lsum0;
        u16t* op = Opart + ((size_t)(ks * 24 + bh) * SEQ + q) * 64;
#pragma unroll
        for (int dh = 0; dh < 2; ++dh) {
            const f32x16& o = dh ? ob : oa;
#pragma unroll
            for (int g = 0; g < 4; ++g) {
                u32x2 pr;
                pr[0] = cvt_pk_bf16(o[4 * g], o[4 * g + 1]);
                pr[1] = cvt_pk_bf16(o[4 * g + 2], o[4 * g + 3]);
                *reinterpret_cast<u32x2*>(op + dh * 32 + 8 * g + 4 * hi) = pr;
            }
        }
        if (!hi)
            Lpart[(size_t)(ks * 24 + bh) * SEQ + q] = ls;
    }
}

// --------------------------------------------- combine k-split partials
// out[b,q,h*64+d] = sum_j O_j / sum_j l_j over 4 k-splits.
__global__ __launch_bounds__(256)
void attn_combine(const u16t* __restrict__ Opart,
                  const float* __restrict__ Lpart, u16t* __restrict__ out)
{
    const int idx = blockIdx.x * 256 + threadIdx.x;   // 0 .. 24*2048*8
    const int dg = idx & 7;
    const int q = (idx >> 3) & 2047;
    const int bh = idx >> 14;
    const int b = bh / 12, h = bh % 12;
    const size_t base = ((size_t)bh * 2048 + q) * 64 + dg * 8;
    const size_t stride = (size_t)24 * 2048 * 64;
    float acc[8] = {0.f, 0.f, 0.f, 0.f, 0.f, 0.f, 0.f, 0.f};
    float l = 0.f;
#pragma unroll
    for (int j = 0; j < 4; ++j) {
        const u32x4 a = *reinterpret_cast<const u32x4*>(Opart + base + j * stride);
#pragma unroll
        for (int m = 0; m < 4; ++m) {
            acc[2 * m]     += bf16_to_f32((u16t)(a[m] & 0xFFFF));
            acc[2 * m + 1] += bf16_to_f32((u16t)(a[m] >> 16));
        }
        l += Lpart[(size_t)j * 24 * 2048 + bh * 2048 + q];
    }
    const float inv = 1.0f / l;
    u32x4 r;
#pragma unroll
    for (int m = 0; m < 4; ++m)
        r[m] = cvt_pk_bf16(acc[2 * m] * inv, acc[2 * m + 1] * inv);
    *reinterpret_cast<u32x4*>(
        out + ((size_t)(b * 2048 + q)) * 768 + h * 64 + dg * 8) = r;
}

// ------------------------------------------------------------------ launch
extern "C" void kernel_launch(void* const* d_in, const int* in_sizes, int n_in,
                              void* d_out, int out_size, void* d_ws, size_t ws_size,
                              hipStream_t stream)
{
    const float* x    = (const float*)d_in[0];
    const float* Wqkv = (const float*)d_in[1];
    const float* Wout = (const float*)d_in[2];
    const float* g1   = (const float*)d_in[3];
    const float* be1  = (const float*)d_in[4];
    const float* g2   = (const float*)d_in[5];
    const float* be2  = (const float*)d_in[6];
    const float* W1   = (const float*)d_in[7];
    const float* b1   = (const float*)d_in[8];
    const float* W2   = (const float*)d_in[9];
    const float* b2   = (const float*)d_in[10];
    const float* ab   = (const float*)d_in[11];
    float* outp = (float*)d_out;

    char* ws = (char*)d_ws;
    size_t off = 0;
    auto alloc = [&](size_t bytes) -> char* {
        char* p = ws + off;
        off += (bytes + 255) & ~(size_t)255;
        return p;
    };

    u16t* WqkvT = (u16t*)alloc((size_t)2304 * 768 * 2);
    u16t* WoutT = (u16t*)alloc((size_t)768 * 768 * 2);
    u16t* W1T   = (u16t*)alloc((size_t)3072 * 768 * 2);
    u16t* W2T   = (u16t*)alloc((size_t)768 * 3072 * 2);
    u16t* h1    = (u16t*)alloc((size_t)4096 * 768 * 2);
    u16t* Qb    = (u16t*)alloc((size_t)24 * 2048 * 64 * 2);
    u16t* Kb    = (u16t*)alloc((size_t)24 * 2048 * 64 * 2);
    u16t* VTb   = (u16t*)alloc((size_t)24 * 64 * 2048 * 2);
    u16t* attnb = (u16t*)alloc((size_t)4096 * 768 * 2);
    float* x1   = (float*)alloc((size_t)4096 * 768 * 4);
    u16t* h2    = (u16t*)alloc((size_t)4096 * 768 * 2);
    u16t* Opart = (u16t*)alloc((size_t)4 * 24 * 2048 * 64 * 2);
    float* Lpart = (float*)alloc((size_t)4 * 24 * 2048 * 4);
    u16t* act   = (u16t*)alloc((size_t)4096 * 3072 * 2);

    // weight prep (all four transposes in one launch)
    transpose_all<<<1728, 256, 0, stream>>>(Wqkv, Wout, W1, W2,
                                            WqkvT, WoutT, W1T, W2T);

    // attention block
    ln_kernel<<<4096, 256, 0, stream>>>(x, g1, be1, h1);
    gemm_kernel<3, 128><<<dim3(32, 18), 256, 0, stream>>>(
        h1, WqkvT, nullptr, nullptr, nullptr, nullptr, Qb, Kb, VTb,
        4096, 2304, 768);
    attn_kernel<<<dim3(16, 12, 4), 256, 0, stream>>>(Qb, Kb, VTb, ab, Opart, Lpart);
    attn_combine<<<(24 * 2048 * 8) / 256, 256, 0, stream>>>(Opart, Lpart, attnb);
    gemm_kernel<1, 64><<<dim3(64, 6), 256, 0, stream>>>(
        attnb, WoutT, x1, nullptr, nullptr, x, nullptr, nullptr, nullptr,
        4096, 768, 768);

    // feed-forward block
    ln_kernel<<<4096, 256, 0, stream>>>(x1, g2, be2, h2);
    gemm_kernel<2, 128><<<dim3(32, 24), 256, 0, stream>>>(
        h2, W1T, nullptr, act, b1, nullptr, nullptr, nullptr, nullptr,
        4096, 3072, 768);
    gemm_kernel<1, 64><<<dim3(64, 6), 256, 0, stream>>>(
        act, W2T, outp, nullptr, b2, x1, nullptr, nullptr, nullptr,
        4096, 768, 3072);
}

// Round 13
// 221.912 us; speedup vs baseline: 1.0226x; 1.0226x over previous
//
#include <hip/hip_runtime.h>

typedef unsigned short u16t;
typedef __bf16 bf16x8 __attribute__((ext_vector_type(8)));
typedef float  f32x4  __attribute__((ext_vector_type(4)));
typedef float  f32x16 __attribute__((ext_vector_type(16)));
typedef unsigned u32x2 __attribute__((ext_vector_type(2)));
typedef unsigned u32x4 __attribute__((ext_vector_type(4)));

#define DEV __device__ __forceinline__

DEV u16t f32_to_bf16(float f) {
    unsigned u = __float_as_uint(f);
    unsigned r = (u + 0x7FFFu + ((u >> 16) & 1u)) >> 16;   // RNE
    return (u16t)r;
}
DEV float bf16_to_f32(u16t u) { return __uint_as_float((unsigned)u << 16); }

DEV unsigned cvt_pk_bf16(float lo, float hi) {
    unsigned r;
    asm("v_cvt_pk_bf16_f32 %0, %1, %2" : "=v"(r) : "v"(lo), "v"(hi));
    return r;
}

DEV float gelu_exact(float x) {
    return 0.5f * x * (1.0f + erff(x * 0.70710678118654752f));
}

DEV void glds16(const void* g, void* l) {
    __builtin_amdgcn_global_load_lds(
        (const __attribute__((address_space(1))) void*)g,
        (__attribute__((address_space(3))) void*)l, 16, 0, 0);
}

#define SCHED_FENCE() __builtin_amdgcn_sched_barrier(0)

// counted-wait + raw barrier pair (attn only)
#define WAITN_BARRIER(N)                                          \
    asm volatile("s_waitcnt vmcnt(" #N ")" ::: "memory");         \
    SCHED_FENCE();                                                \
    __builtin_amdgcn_s_barrier();                                 \
    SCHED_FENCE();

#define PLAIN_BARRIER()                                           \
    SCHED_FENCE();                                                \
    __builtin_amdgcn_s_barrier();                                 \
    SCHED_FENCE();

// ---------------------------------------------------------------- LayerNorm
// one block (192 thr, 3 waves) per row of 768; float4 loads, bf16x4 stores
__global__ __launch_bounds__(192)
void ln_kernel(const float* __restrict__ x, const float* __restrict__ g,
               const float* __restrict__ b, u16t* __restrict__ out)
{
    const int row = blockIdx.x;
    const int t = threadIdx.x;
    const f32x4 v = *reinterpret_cast<const f32x4*>(x + (size_t)row * 768 + t * 4);
    float s  = v[0] + v[1] + v[2] + v[3];
    float s2 = v[0] * v[0] + v[1] * v[1] + v[2] * v[2] + v[3] * v[3];
#pragma unroll
    for (int off = 32; off > 0; off >>= 1) {
        s  += __shfl_xor(s, off);
        s2 += __shfl_xor(s2, off);
    }
    __shared__ float sm[6];
    const int w = t >> 6;
    if ((t & 63) == 0) { sm[w] = s; sm[3 + w] = s2; }
    __syncthreads();
    s  = sm[0] + sm[1] + sm[2];
    s2 = sm[3] + sm[4] + sm[5];
    const float mu  = s * (1.0f / 768.0f);
    const float var = fmaxf(s2 * (1.0f / 768.0f) - mu * mu, 0.0f);
    const float rst = rsqrtf(var + 1e-5f);
    const f32x4 gv = *reinterpret_cast<const f32x4*>(g + t * 4);
    const f32x4 bv = *reinterpret_cast<const f32x4*>(b + t * 4);
    u32x2 r;
    r[0] = cvt_pk_bf16((v[0] - mu) * rst * gv[0] + bv[0],
                       (v[1] - mu) * rst * gv[1] + bv[1]);
    r[1] = cvt_pk_bf16((v[2] - mu) * rst * gv[2] + bv[2],
                       (v[3] - mu) * rst * gv[3] + bv[3]);
    *reinterpret_cast<u32x2*>(out + (size_t)row * 768 + t * 4) = r;
}

// ----------------------------------- all 4 weight transposes in one launch
__global__ __launch_bounds__(256)
void transpose_all(const float* __restrict__ Wqkv, const float* __restrict__ Wout,
                   const float* __restrict__ W1, const float* __restrict__ W2,
                   u16t* __restrict__ WqkvT, u16t* __restrict__ WoutT,
                   u16t* __restrict__ W1T, u16t* __restrict__ W2T)
{
    int b = blockIdx.x;
    const float* in; u16t* out; int R, C, cx, ry;
    if (b < 432)       { in = Wqkv; out = WqkvT; R = 768;  C = 2304; cx = b % 36; ry = b / 36; }
    else if (b < 576)  { b -= 432;  in = Wout; out = WoutT; R = 768;  C = 768;  cx = b % 12; ry = b / 12; }
    else if (b < 1152) { b -= 576;  in = W1;   out = W1T;   R = 768;  C = 3072; cx = b % 48; ry = b / 48; }
    else               { b -= 1152; in = W2;   out = W2T;   R = 3072; C = 768;  cx = b % 12; ry = b / 12; }
    __shared__ float tile[64][65];
    const int c0 = cx * 64, r0 = ry * 64;
    const int t = threadIdx.x;
#pragma unroll
    for (int j = 0; j < 16; ++j) {
        const int idx = j * 256 + t;
        const int rl = idx >> 6, cl = idx & 63;
        tile[rl][cl] = in[(size_t)(r0 + rl) * C + c0 + cl];
    }
    __syncthreads();
#pragma unroll
    for (int j = 0; j < 16; ++j) {
        const int idx = j * 256 + t;
        const int cl = idx >> 6, rl = idx & 63;
        out[(size_t)(c0 + cl) * R + r0 + rl] = f32_to_bf16(tile[rl][cl]);
    }
}

// ------------------------------------------------------------------- GEMM
// C[M,N] = A[M,K] * BT[N,K]^T, bf16 in, TM x 128 tile (TM=128 or 64), BK=64,
// m97-style SINGLE-buffered LDS (32/24 KB -> 5-6 blocks/CU) with plain
// __syncthreads pairs; 128B-row slot-XOR swizzle (both sides). Implicit
// cross-block wave overlap does the latency hiding (m114).
// MODE 0: f32. MODE 1: +res(+bias) f32. MODE 2: gelu(acc+bias) bf16.
// MODE 3: qkv epilogue -> Q,K [B*H,N,64] bf16 + VT [B*H,64,N] (TM=128 only).
template <int MODE, int TM>
__global__ __launch_bounds__(256)
void gemm_kernel(const u16t* __restrict__ A, const u16t* __restrict__ BT,
                 float* __restrict__ Cf, u16t* __restrict__ Cb,
                 const float* __restrict__ bias, const float* __restrict__ res,
                 u16t* __restrict__ Qo, u16t* __restrict__ Ko,
                 u16t* __restrict__ VTo,
                 int M, int Nn, int K)
{
    constexpr int MI = TM / 32;          // acc row-frags per wave (4 or 2)
    constexpr int ABYTES = TM * 128;     // A tile bytes
    __shared__ __align__(16) char gsm[ABYTES + 16384];
    const int t = threadIdx.x;
    const int w = t >> 6, lane = t & 63;
    const int l16 = lane & 15, lhi = lane >> 4;
    const int wr = w >> 1, wc = w & 1;
    const int m0 = blockIdx.x * TM, n0 = blockIdx.y * 128;

    const f32x4 fz = {0.f, 0.f, 0.f, 0.f};
    f32x4 acc[MI][4];
#pragma unroll
    for (int i = 0; i < MI; ++i)
#pragma unroll
        for (int j = 0; j < 4; ++j) acc[i][j] = fz;

    // staging: rows of 128B (64 bf16). Round i covers 32 rows; thread t ->
    // row i*32 + (t>>3), dest slot t&7 (linear), src slot (t&7)^((t>>3)&7).
    const int rbase = t >> 3;                       // 0..31
    const int ssrc = ((t & 7) ^ (rbase & 7)) * 16;  // pre-swizzled src slot

    auto stage = [&](int kt) {
#pragma unroll
        for (int i = 0; i < TM / 32; ++i) {
            const int row = i * 32 + rbase;
            glds16((const char*)A + ((size_t)(m0 + row) * K + kt) * 2 + ssrc,
                   gsm + i * 4096 + t * 16);
        }
#pragma unroll
        for (int i = 0; i < 4; ++i) {
            const int row = i * 32 + rbase;
            glds16((const char*)BT + ((size_t)(n0 + row) * K + kt) * 2 + ssrc,
                   gsm + ABYTES + i * 4096 + t * 16);
        }
    };

    auto body = [&]() {
        const char* Ab = gsm;
        const char* Bb = gsm + ABYTES;
#pragma unroll
        for (int ks = 0; ks < 2; ++ks) {        // kk = 0, 32
            const int wsl = lhi + 4 * ks;
            bf16x8 af[MI], bfv[4];
#pragma unroll
            for (int i = 0; i < MI; ++i) {
                const int row = 16 * MI * wr + 16 * i + l16;
                af[i] = *reinterpret_cast<const bf16x8*>(
                    Ab + row * 128 + ((wsl ^ (row & 7)) << 4));
            }
#pragma unroll
            for (int j = 0; j < 4; ++j) {
                const int row = 64 * wc + 16 * j + l16;
                bfv[j] = *reinterpret_cast<const bf16x8*>(
                    Bb + row * 128 + ((wsl ^ (row & 7)) << 4));
            }
#pragma unroll
            for (int i = 0; i < MI; ++i)
#pragma unroll
                for (int j = 0; j < 4; ++j)
                    acc[i][j] = __builtin_amdgcn_mfma_f32_16x16x32_bf16(
                        af[i], bfv[j], acc[i][j], 0, 0, 0);
        }
    };

    for (int kt = 0; kt < K; kt += 64) {
        stage(kt);
        __syncthreads();        // compiler inserts vmcnt(0) drain
        body();
        __syncthreads();        // protect LDS before next stage
    }

    const int rb = m0 + 16 * MI * wr + 4 * lhi;
    const int cb = n0 + 64 * wc + l16;

    if constexpr (MODE == 3) {
        const int qi = n0 / 768;
        const int b = rb >> 11;
        const int nn0 = rb & 2047;
#pragma unroll
        for (int j = 0; j < 4; ++j) {
            const int c = cb - qi * 768 + 16 * j;   // 0..767
            const int h = c >> 6, d = c & 63;
            if (qi < 2) {
                u16t* dst = (qi == 0) ? Qo : Ko;
                const size_t base = ((size_t)(b * 12 + h) * 2048 + nn0) * 64 + d;
#pragma unroll
                for (int i = 0; i < MI; ++i)
#pragma unroll
                    for (int r = 0; r < 4; ++r)
                        dst[base + (size_t)(16 * i + r) * 64] =
                            f32_to_bf16(acc[i][j][r]);
            } else {
                u16t* dst = VTo + ((size_t)(b * 12 + h) * 64 + d) * 2048 + nn0;
#pragma unroll
                for (int i = 0; i < MI; ++i) {
                    u32x2 pr;
                    pr[0] = cvt_pk_bf16(acc[i][j][0], acc[i][j][1]);
                    pr[1] = cvt_pk_bf16(acc[i][j][2], acc[i][j][3]);
                    *reinterpret_cast<u32x2*>(dst + 16 * i) = pr;
                }
            }
        }
        return;
    }

#pragma unroll
    for (int i = 0; i < MI; ++i) {
#pragma unroll
        for (int j = 0; j < 4; ++j) {
#pragma unroll
            for (int r = 0; r < 4; ++r) {
                const int row = rb + 16 * i + r;
                const int col = cb + 16 * j;
                float v = acc[i][j][r];
                if (MODE == 0) {
                    Cf[(size_t)row * Nn + col] = v;
                } else if (MODE == 1) {
                    v += res[(size_t)row * Nn + col];
                    if (bias) v += bias[col];
                    Cf[(size_t)row * Nn + col] = v;
                } else if (MODE == 2) {
                    v = gelu_exact(v + bias[col]);
                    Cb[(size_t)row * Nn + col] = f32_to_bf16(v);
                }
            }
        }
    }
}

// ------------------------------------------------------- flash attention
// R9-proven config: swapped-operand 32x32 MFMA, 2-batch fused (bias staged
// once, shared), all streams via glds into a full double buffer (64KB ->
// 2 blocks/CU), counted vmcnt(8)+barrier. Max-free softmax, 4-way k-split.
// grid (16 qblk, 12 h, 4 ks), block 256.
__global__ __launch_bounds__(256, 2)
void attn_kernel(const u16t* __restrict__ Q, const u16t* __restrict__ K,
                 const u16t* __restrict__ VT, const float* __restrict__ bias,
                 u16t* __restrict__ Opart, float* __restrict__ Lpart)
{
    const int SEQ = 2048;
    const int h = blockIdx.y;
    const int ks = blockIdx.z;
    const int t = threadIdx.x;
    const int w = t >> 6, lane = t & 63;
    const int l32 = lane & 31, hi = lane >> 5;
    const int q = blockIdx.x * 128 + w * 32 + l32;
    const int bh0 = h, bh1 = 12 + h;

    // per 32KB buffer: [0,16K) bias [128q][128B=32k f32] swz row&7
    //   [16K) K0 [32k][128B] swz row&7 | [20K) K1 | [24K) V0 [64d][64B]
    //   swz (row>>1)&3 | [28K) V1.  Two buffers (64KB total).
    __shared__ __align__(16) char smem[65536];

    const u16t* qp0 = Q + ((size_t)bh0 * SEQ + q) * 64 + 8 * hi;
    const u16t* qp1 = Q + ((size_t)bh1 * SEQ + q) * 64 + 8 * hi;
    bf16x8 qf0[4], qf1[4];
#pragma unroll
    for (int dseg = 0; dseg < 4; ++dseg) {
        qf0[dseg] = *reinterpret_cast<const bf16x8*>(qp0 + dseg * 16);
        qf1[dseg] = *reinterpret_cast<const bf16x8*>(qp1 + dseg * 16);
    }

    const char* kg0 = (const char*)K + (size_t)bh0 * SEQ * 128;    // 128B rows
    const char* kg1 = (const char*)K + (size_t)bh1 * SEQ * 128;
    const char* vg0 = (const char*)VT + (size_t)bh0 * 64 * 4096;   // 4KB rows
    const char* vg1 = (const char*)VT + (size_t)bh1 * 64 * 4096;
    const char* bg = (const char*)bias +
                     ((size_t)h * SEQ + blockIdx.x * 128) * 8192;  // 8KB rows

    const int srow8 = lane >> 3;                        // 0..7
    const int sslotK = ((lane & 7) ^ srow8) * 16;       // 128B-row swizzle
    const int vrow  = w * 16 + (lane >> 2);             // 0..63
    const int sslotV = ((lane & 3) ^ ((vrow >> 1) & 3)) * 16;

    auto stage_all = [&](int bb, int k0) {              // 8 glds per wave
#pragma unroll
        for (int i = 0; i < 4; ++i) {
            const int row = 32 * w + 8 * i + srow8;
            glds16(bg + (size_t)row * 8192 + (size_t)k0 * 4 + sslotK,
                   smem + bb + 4096 * w + i * 1024);
        }
        glds16(kg0 + (size_t)(k0 + 8 * w + srow8) * 128 + sslotK,
               smem + bb + 16384 + w * 1024);
        glds16(kg1 + (size_t)(k0 + 8 * w + srow8) * 128 + sslotK,
               smem + bb + 20480 + w * 1024);
        glds16(vg0 + (size_t)vrow * 4096 + (size_t)k0 * 2 + sslotV,
               smem + bb + 24576 + w * 1024);
        glds16(vg1 + (size_t)vrow * 4096 + (size_t)k0 * 2 + sslotV,
               smem + bb + 28672 + w * 1024);
    };

    const int rsw = l32 & 7;
    int boff[4], koff[4];
#pragma unroll
    for (int g = 0; g < 4; ++g)
        boff[g] = (32 * w + l32) * 128 + ((((g << 1) + hi) ^ rsw) << 4);
#pragma unroll
    for (int dseg = 0; dseg < 4; ++dseg)
        koff[dseg] = l32 * 128 + ((((dseg << 1) + hi) ^ rsw) << 4);
    const int vr3 = (l32 >> 1) & 3;
    const int voff00 = l32 * 64 + ((hi ^ vr3) << 4);
    const int voff01 = l32 * 64 + (((2 + hi) ^ vr3) << 4);
    const int voff10 = voff00 + 32 * 64;
    const int voff11 = voff01 + 32 * 64;

    f32x16 o00, o01, o10, o11;   // [batch][d-half]
#pragma unroll
    for (int i = 0; i < 16; ++i) { o00[i] = 0.f; o01[i] = 0.f;
                                   o10[i] = 0.f; o11[i] = 0.f; }
    float lsum0 = 0.f, lsum1 = 0.f;

    auto batch_body = [&](const bf16x8 (&qf)[4], int kvbase, int vbase,
                          const f32x4 (&bv)[4], f32x16& oa, f32x16& ob,
                          float& lsum) {
        f32x16 st;
#pragma unroll
        for (int i = 0; i < 16; ++i) st[i] = 0.f;
#pragma unroll
        for (int dseg = 0; dseg < 4; ++dseg) {
            bf16x8 kf = *reinterpret_cast<const bf16x8*>(
                smem + kvbase + koff[dseg]);
            st = __builtin_amdgcn_mfma_f32_32x32x16_bf16(kf, qf[dseg], st, 0, 0, 0);
        }
        unsigned pk[8];
#pragma unroll
        for (int i2 = 0; i2 < 8; ++i2) {
            const int ia = 2 * i2, ib = 2 * i2 + 1;
            const float pa = __expf(st[ia] * 0.125f + bv[ia >> 2][ia & 3]);
            const float pb = __expf(st[ib] * 0.125f + bv[ib >> 2][ib & 3]);
            lsum += pa + pb;
            pk[i2] = cvt_pk_bf16(pa, pb);
        }
        unsigned sx[8];
#pragma unroll
        for (int i2 = 0; i2 < 8; ++i2)
            sx[i2] = (unsigned)__shfl_xor((int)pk[i2], 32);
        union { unsigned u[4]; bf16x8 v; } B0, B1;
        B0.u[0] = hi ? sx[2] : pk[0];
        B0.u[1] = hi ? sx[3] : pk[1];
        B0.u[2] = hi ? pk[2] : sx[0];
        B0.u[3] = hi ? pk[3] : sx[1];
        B1.u[0] = hi ? sx[6] : pk[4];
        B1.u[1] = hi ? sx[7] : pk[5];
        B1.u[2] = hi ? pk[6] : sx[4];
        B1.u[3] = hi ? pk[7] : sx[5];
        bf16x8 v00 = *reinterpret_cast<const bf16x8*>(smem + vbase + voff00);
        bf16x8 v01 = *reinterpret_cast<const bf16x8*>(smem + vbase + voff01);
        bf16x8 v10 = *reinterpret_cast<const bf16x8*>(smem + vbase + voff10);
        bf16x8 v11 = *reinterpret_cast<const bf16x8*>(smem + vbase + voff11);
        oa = __builtin_amdgcn_mfma_f32_32x32x16_bf16(v00, B0.v, oa, 0, 0, 0);
        oa = __builtin_amdgcn_mfma_f32_32x32x16_bf16(v01, B1.v, oa, 0, 0, 0);
        ob = __builtin_amdgcn_mfma_f32_32x32x16_bf16(v10, B0.v, ob, 0, 0, 0);
        ob = __builtin_amdgcn_mfma_f32_32x32x16_bf16(v11, B1.v, ob, 0, 0, 0);
    };

    const int kbeg = ks * 512;

    stage_all(0, kbeg);
    WAITN_BARRIER(0)

    int cur = 0;
    for (int i = 0; i < 16; ++i) {
        const int k0 = kbeg + 32 * i;
        if (i < 15) {
            stage_all(cur ^ 32768, k0 + 32);   // 8 glds: tile i+1
            WAITN_BARRIER(8)                   // retires tile i's 8 glds
        } else {
            WAITN_BARRIER(0)
        }
        {
            f32x4 bv[4];
#pragma unroll
            for (int g = 0; g < 4; ++g)
                bv[g] = *reinterpret_cast<const f32x4*>(smem + cur + boff[g]);
            batch_body(qf0, cur + 16384, cur + 24576, bv, o00, o01, lsum0);
            batch_body(qf1, cur + 20480, cur + 28672, bv, o10, o11, lsum1);
        }
        PLAIN_BARRIER()                        // all waves done reading buf cur
        cur ^= 32768;
    }

    lsum0 += __shfl_xor(lsum0, 32);
    lsum1 += __shfl_xor(lsum1, 32);

#pragma unroll
    for (int beta = 0; beta < 2; ++beta) {
        const int bh = beta ? bh1 : bh0;
        const f32x16& oa = beta ? o10 : o00;
        const f32x16& ob = beta ? o11 : o01;
        const float ls = beta ? lsum1 : lsum0;
        u16t* op = Opart + ((size_t)(ks * 24 + bh) * SEQ + q) * 64;
#pragma unroll
        for (int dh = 0; dh < 2; ++dh) {
            const f32x16& o = dh ? ob : oa;
#pragma unroll
            for (int g = 0; g < 4; ++g) {
                u32x2 pr;
                pr[0] = cvt_pk_bf16(o[4 * g], o[4 * g + 1]);
                pr[1] = cvt_pk_bf16(o[4 * g + 2], o[4 * g + 3]);
                *reinterpret_cast<u32x2*>(op + dh * 32 + 8 * g + 4 * hi) = pr;
            }
        }
        if (!hi)
            Lpart[(size_t)(ks * 24 + bh) * SEQ + q] = ls;
    }
}

// --------------------------------------------- combine k-split partials
// out[b,q,h*64+d] = sum_j O_j / sum_j l_j over 4 k-splits.
__global__ __launch_bounds__(256)
void attn_combine(const u16t* __restrict__ Opart,
                  const float* __restrict__ Lpart, u16t* __restrict__ out)
{
    const int idx = blockIdx.x * 256 + threadIdx.x;   // 0 .. 24*2048*8
    const int dg = idx & 7;
    const int q = (idx >> 3) & 2047;
    const int bh = idx >> 14;
    const int b = bh / 12, h = bh % 12;
    const size_t base = ((size_t)bh * 2048 + q) * 64 + dg * 8;
    const size_t stride = (size_t)24 * 2048 * 64;
    float acc[8] = {0.f, 0.f, 0.f, 0.f, 0.f, 0.f, 0.f, 0.f};
    float l = 0.f;
#pragma unroll
    for (int j = 0; j < 4; ++j) {
        const u32x4 a = *reinterpret_cast<const u32x4*>(Opart + base + j * stride);
#pragma unroll
        for (int m = 0; m < 4; ++m) {
            acc[2 * m]     += bf16_to_f32((u16t)(a[m] & 0xFFFF));
            acc[2 * m + 1] += bf16_to_f32((u16t)(a[m] >> 16));
        }
        l += Lpart[(size_t)j * 24 * 2048 + bh * 2048 + q];
    }
    const float inv = 1.0f / l;
    u32x4 r;
#pragma unroll
    for (int m = 0; m < 4; ++m)
        r[m] = cvt_pk_bf16(acc[2 * m] * inv, acc[2 * m + 1] * inv);
    *reinterpret_cast<u32x4*>(
        out + ((size_t)(b * 2048 + q)) * 768 + h * 64 + dg * 8) = r;
}

// ------------------------------------------------------------------ launch
extern "C" void kernel_launch(void* const* d_in, const int* in_sizes, int n_in,
                              void* d_out, int out_size, void* d_ws, size_t ws_size,
                              hipStream_t stream)
{
    const float* x    = (const float*)d_in[0];
    const float* Wqkv = (const float*)d_in[1];
    const float* Wout = (const float*)d_in[2];
    const float* g1   = (const float*)d_in[3];
    const float* be1  = (const float*)d_in[4];
    const float* g2   = (const float*)d_in[5];
    const float* be2  = (const float*)d_in[6];
    const float* W1   = (const float*)d_in[7];
    const float* b1   = (const float*)d_in[8];
    const float* W2   = (const float*)d_in[9];
    const float* b2   = (const float*)d_in[10];
    const float* ab   = (const float*)d_in[11];
    float* outp = (float*)d_out;

    char* ws = (char*)d_ws;
    size_t off = 0;
    auto alloc = [&](size_t bytes) -> char* {
        char* p = ws + off;
        off += (bytes + 255) & ~(size_t)255;
        return p;
    };

    u16t* WqkvT = (u16t*)alloc((size_t)2304 * 768 * 2);
    u16t* WoutT = (u16t*)alloc((size_t)768 * 768 * 2);
    u16t* W1T   = (u16t*)alloc((size_t)3072 * 768 * 2);
    u16t* W2T   = (u16t*)alloc((size_t)768 * 3072 * 2);
    u16t* h1    = (u16t*)alloc((size_t)4096 * 768 * 2);
    u16t* Qb    = (u16t*)alloc((size_t)24 * 2048 * 64 * 2);
    u16t* Kb    = (u16t*)alloc((size_t)24 * 2048 * 64 * 2);
    u16t* VTb   = (u16t*)alloc((size_t)24 * 64 * 2048 * 2);
    u16t* attnb = (u16t*)alloc((size_t)4096 * 768 * 2);
    float* x1   = (float*)alloc((size_t)4096 * 768 * 4);
    u16t* h2    = (u16t*)alloc((size_t)4096 * 768 * 2);
    u16t* Opart = (u16t*)alloc((size_t)4 * 24 * 2048 * 64 * 2);
    float* Lpart = (float*)alloc((size_t)4 * 24 * 2048 * 4);
    u16t* act   = (u16t*)alloc((size_t)4096 * 3072 * 2);

    // weight prep (all four transposes in one launch)
    transpose_all<<<1728, 256, 0, stream>>>(Wqkv, Wout, W1, W2,
                                            WqkvT, WoutT, W1T, W2T);

    // attention block
    ln_kernel<<<4096, 192, 0, stream>>>(x, g1, be1, h1);
    gemm_kernel<3, 128><<<dim3(32, 18), 256, 0, stream>>>(
        h1, WqkvT, nullptr, nullptr, nullptr, nullptr, Qb, Kb, VTb,
        4096, 2304, 768);
    attn_kernel<<<dim3(16, 12, 4), 256, 0, stream>>>(Qb, Kb, VTb, ab, Opart, Lpart);
    attn_combine<<<(24 * 2048 * 8) / 256, 256, 0, stream>>>(Opart, Lpart, attnb);
    gemm_kernel<1, 64><<<dim3(64, 6), 256, 0, stream>>>(
        attnb, WoutT, x1, nullptr, nullptr, x, nullptr, nullptr, nullptr,
        4096, 768, 768);

    // feed-forward block
    ln_kernel<<<4096, 192, 0, stream>>>(x1, g2, be2, h2);
    gemm_kernel<2, 128><<<dim3(32, 24), 256, 0, stream>>>(
        h2, W1T, nullptr, act, b1, nullptr, nullptr, nullptr, nullptr,
        4096, 3072, 768);
    gemm_kernel<1, 64><<<dim3(64, 6), 256, 0, stream>>>(
        act, W2T, outp, nullptr, b2, x1, nullptr, nullptr, nullptr,
        4096, 768, 3072);
}

// Round 14
// 205.493 us; speedup vs baseline: 1.1043x; 1.0799x over previous
//
#include <hip/hip_runtime.h>

typedef unsigned short u16t;
typedef __bf16 bf16x8 __attribute__((ext_vector_type(8)));
typedef float  f32x4  __attribute__((ext_vector_type(4)));
typedef float  f32x16 __attribute__((ext_vector_type(16)));
typedef unsigned u32x2 __attribute__((ext_vector_type(2)));
typedef unsigned u32x4 __attribute__((ext_vector_type(4)));

#define DEV __device__ __forceinline__

DEV u16t f32_to_bf16(float f) {
    unsigned u = __float_as_uint(f);
    unsigned r = (u + 0x7FFFu + ((u >> 16) & 1u)) >> 16;   // RNE
    return (u16t)r;
}
DEV float bf16_to_f32(u16t u) { return __uint_as_float((unsigned)u << 16); }

DEV unsigned cvt_pk_bf16(float lo, float hi) {
    unsigned r;
    asm("v_cvt_pk_bf16_f32 %0, %1, %2" : "=v"(r) : "v"(lo), "v"(hi));
    return r;
}

DEV float gelu_exact(float x) {
    return 0.5f * x * (1.0f + erff(x * 0.70710678118654752f));
}

DEV void glds16(const void* g, void* l) {
    __builtin_amdgcn_global_load_lds(
        (const __attribute__((address_space(1))) void*)g,
        (__attribute__((address_space(3))) void*)l, 16, 0, 0);
}

#define SCHED_FENCE() __builtin_amdgcn_sched_barrier(0)

// counted-wait + raw barrier pair (never drain in-flight prefetch)
#define WAITN_BARRIER(N)                                          \
    asm volatile("s_waitcnt vmcnt(" #N ")" ::: "memory");         \
    SCHED_FENCE();                                                \
    __builtin_amdgcn_s_barrier();                                 \
    SCHED_FENCE();

#define PLAIN_BARRIER()                                           \
    SCHED_FENCE();                                                \
    __builtin_amdgcn_s_barrier();                                 \
    SCHED_FENCE();

// ---------------------------------------------------------------- LayerNorm
// one block (192 thr, 3 waves) per row of 768; INBF: input bf16 else f32.
template <bool INBF>
__global__ __launch_bounds__(192)
void ln_kernel(const void* __restrict__ xin, const float* __restrict__ g,
               const float* __restrict__ b, u16t* __restrict__ out)
{
    const int row = blockIdx.x;
    const int t = threadIdx.x;
    f32x4 v;
    if constexpr (INBF) {
        const u32x2 ld = *reinterpret_cast<const u32x2*>(
            (const u16t*)xin + (size_t)row * 768 + t * 4);
        v[0] = bf16_to_f32((u16t)(ld[0] & 0xFFFF));
        v[1] = bf16_to_f32((u16t)(ld[0] >> 16));
        v[2] = bf16_to_f32((u16t)(ld[1] & 0xFFFF));
        v[3] = bf16_to_f32((u16t)(ld[1] >> 16));
    } else {
        v = *reinterpret_cast<const f32x4*>(
            (const float*)xin + (size_t)row * 768 + t * 4);
    }
    float s  = v[0] + v[1] + v[2] + v[3];
    float s2 = v[0] * v[0] + v[1] * v[1] + v[2] * v[2] + v[3] * v[3];
#pragma unroll
    for (int off = 32; off > 0; off >>= 1) {
        s  += __shfl_xor(s, off);
        s2 += __shfl_xor(s2, off);
    }
    __shared__ float sm[6];
    const int w = t >> 6;
    if ((t & 63) == 0) { sm[w] = s; sm[3 + w] = s2; }
    __syncthreads();
    s  = sm[0] + sm[1] + sm[2];
    s2 = sm[3] + sm[4] + sm[5];
    const float mu  = s * (1.0f / 768.0f);
    const float var = fmaxf(s2 * (1.0f / 768.0f) - mu * mu, 0.0f);
    const float rst = rsqrtf(var + 1e-5f);
    const f32x4 gv = *reinterpret_cast<const f32x4*>(g + t * 4);
    const f32x4 bv = *reinterpret_cast<const f32x4*>(b + t * 4);
    u32x2 r;
    r[0] = cvt_pk_bf16((v[0] - mu) * rst * gv[0] + bv[0],
                       (v[1] - mu) * rst * gv[1] + bv[1]);
    r[1] = cvt_pk_bf16((v[2] - mu) * rst * gv[2] + bv[2],
                       (v[3] - mu) * rst * gv[3] + bv[3]);
    *reinterpret_cast<u32x2*>(out + (size_t)row * 768 + t * 4) = r;
}

// ----------------------------------- all 4 weight transposes in one launch
__global__ __launch_bounds__(256)
void transpose_all(const float* __restrict__ Wqkv, const float* __restrict__ Wout,
                   const float* __restrict__ W1, const float* __restrict__ W2,
                   u16t* __restrict__ WqkvT, u16t* __restrict__ WoutT,
                   u16t* __restrict__ W1T, u16t* __restrict__ W2T)
{
    int b = blockIdx.x;
    const float* in; u16t* out; int R, C, cx, ry;
    if (b < 432)       { in = Wqkv; out = WqkvT; R = 768;  C = 2304; cx = b % 36; ry = b / 36; }
    else if (b < 576)  { b -= 432;  in = Wout; out = WoutT; R = 768;  C = 768;  cx = b % 12; ry = b / 12; }
    else if (b < 1152) { b -= 576;  in = W1;   out = W1T;   R = 768;  C = 3072; cx = b % 48; ry = b / 48; }
    else               { b -= 1152; in = W2;   out = W2T;   R = 3072; C = 768;  cx = b % 12; ry = b / 12; }
    __shared__ float tile[64][65];
    const int c0 = cx * 64, r0 = ry * 64;
    const int t = threadIdx.x;
#pragma unroll
    for (int j = 0; j < 16; ++j) {
        const int idx = j * 256 + t;
        const int rl = idx >> 6, cl = idx & 63;
        tile[rl][cl] = in[(size_t)(r0 + rl) * C + c0 + cl];
    }
    __syncthreads();
#pragma unroll
    for (int j = 0; j < 16; ++j) {
        const int idx = j * 256 + t;
        const int cl = idx >> 6, rl = idx & 63;
        out[(size_t)(c0 + cl) * R + r0 + rl] = f32_to_bf16(tile[rl][cl]);
    }
}

// ------------------------------------------------------------------- GEMM
// C[M,N] = A[M,K] * BT[N,K]^T, bf16 in, TM x 128 tile, BK=64, 128B-row
// slot-XOR swizzle (both sides).
// DBUF=false: single-buffer + __syncthreads (for grids with >=2 blocks/CU:
//   implicit cross-block overlap hides latency, m114).
// DBUF=true: double-buffer + counted vmcnt (for low-block-count grids at
//   ~1.5 waves/SIMD where ILP must hide latency).
// MODE 0: f32. MODE 1: +res(+bias), res f32 or bf16 (RESBF), out f32 or
// bf16 (OUTBF). MODE 2: gelu(acc+bias) bf16. MODE 3: qkv epilogue.
template <int MODE, int TM, bool DBUF, bool OUTBF, bool RESBF>
__global__ __launch_bounds__(256)
void gemm_kernel(const u16t* __restrict__ A, const u16t* __restrict__ BT,
                 float* __restrict__ Cf, u16t* __restrict__ Cb,
                 const float* __restrict__ bias, const float* __restrict__ res,
                 const u16t* __restrict__ resb,
                 u16t* __restrict__ Qo, u16t* __restrict__ Ko,
                 u16t* __restrict__ VTo,
                 int M, int Nn, int K)
{
    constexpr int MI = TM / 32;          // acc row-frags per wave (4 or 2)
    constexpr int ABYTES = TM * 128;     // A tile bytes per buffer
    constexpr int BUFB = ABYTES + 16384; // buffer stride
    __shared__ __align__(16) char gsm[(DBUF ? 2 : 1) * BUFB];
    const int t = threadIdx.x;
    const int w = t >> 6, lane = t & 63;
    const int l16 = lane & 15, lhi = lane >> 4;
    const int wr = w >> 1, wc = w & 1;
    const int m0 = blockIdx.x * TM, n0 = blockIdx.y * 128;

    const f32x4 fz = {0.f, 0.f, 0.f, 0.f};
    f32x4 acc[MI][4];
#pragma unroll
    for (int i = 0; i < MI; ++i)
#pragma unroll
        for (int j = 0; j < 4; ++j) acc[i][j] = fz;

    // staging: rows of 128B (64 bf16). Round i covers 32 rows; thread t ->
    // row i*32 + (t>>3), dest slot t&7 (linear), src slot (t&7)^((t>>3)&7).
    const int rbase = t >> 3;                       // 0..31
    const int ssrc = ((t & 7) ^ (rbase & 7)) * 16;  // pre-swizzled src slot

    auto stage = [&](int bufb, int kt) {
#pragma unroll
        for (int i = 0; i < TM / 32; ++i) {
            const int row = i * 32 + rbase;
            glds16((const char*)A + ((size_t)(m0 + row) * K + kt) * 2 + ssrc,
                   gsm + bufb + i * 4096 + t * 16);
        }
#pragma unroll
        for (int i = 0; i < 4; ++i) {
            const int row = i * 32 + rbase;
            glds16((const char*)BT + ((size_t)(n0 + row) * K + kt) * 2 + ssrc,
                   gsm + bufb + ABYTES + i * 4096 + t * 16);
        }
    };

    auto body = [&](int bufb) {
        const char* Ab = gsm + bufb;
        const char* Bb = gsm + bufb + ABYTES;
#pragma unroll
        for (int ks = 0; ks < 2; ++ks) {        // kk = 0, 32
            const int wsl = lhi + 4 * ks;
            bf16x8 af[MI], bfv[4];
#pragma unroll
            for (int i = 0; i < MI; ++i) {
                const int row = 16 * MI * wr + 16 * i + l16;
                af[i] = *reinterpret_cast<const bf16x8*>(
                    Ab + row * 128 + ((wsl ^ (row & 7)) << 4));
            }
#pragma unroll
            for (int j = 0; j < 4; ++j) {
                const int row = 64 * wc + 16 * j + l16;
                bfv[j] = *reinterpret_cast<const bf16x8*>(
                    Bb + row * 128 + ((wsl ^ (row & 7)) << 4));
            }
#pragma unroll
            for (int i = 0; i < MI; ++i)
#pragma unroll
                for (int j = 0; j < 4; ++j)
                    acc[i][j] = __builtin_amdgcn_mfma_f32_16x16x32_bf16(
                        af[i], bfv[j], acc[i][j], 0, 0, 0);
        }
    };

    if constexpr (DBUF) {
        stage(0, 0);
        int bufb = 0;
        for (int kt = 0; kt + 64 < K; kt += 64) {
            stage(bufb ^ BUFB, kt + 64);
            if constexpr (TM == 128) { WAITN_BARRIER(8) }
            else                     { WAITN_BARRIER(6) }
            body(bufb);
            PLAIN_BARRIER()
            bufb ^= BUFB;
        }
        WAITN_BARRIER(0)
        body(bufb);
    } else {
        for (int kt = 0; kt < K; kt += 64) {
            stage(0, kt);
            __syncthreads();        // compiler inserts vmcnt(0) drain
            body(0);
            __syncthreads();        // protect LDS before next stage
        }
    }

    const int rb = m0 + 16 * MI * wr + 4 * lhi;
    const int cb = n0 + 64 * wc + l16;

    if constexpr (MODE == 3) {
        const int qi = n0 / 768;
        const int b = rb >> 11;
        const int nn0 = rb & 2047;
#pragma unroll
        for (int j = 0; j < 4; ++j) {
            const int c = cb - qi * 768 + 16 * j;   // 0..767
            const int h = c >> 6, d = c & 63;
            if (qi < 2) {
                u16t* dst = (qi == 0) ? Qo : Ko;
                const size_t base = ((size_t)(b * 12 + h) * 2048 + nn0) * 64 + d;
#pragma unroll
                for (int i = 0; i < MI; ++i)
#pragma unroll
                    for (int r = 0; r < 4; ++r)
                        dst[base + (size_t)(16 * i + r) * 64] =
                            f32_to_bf16(acc[i][j][r]);
            } else {
                u16t* dst = VTo + ((size_t)(b * 12 + h) * 64 + d) * 2048 + nn0;
#pragma unroll
                for (int i = 0; i < MI; ++i) {
                    u32x2 pr;
                    pr[0] = cvt_pk_bf16(acc[i][j][0], acc[i][j][1]);
                    pr[1] = cvt_pk_bf16(acc[i][j][2], acc[i][j][3]);
                    *reinterpret_cast<u32x2*>(dst + 16 * i) = pr;
                }
            }
        }
        return;
    }

#pragma unroll
    for (int i = 0; i < MI; ++i) {
#pragma unroll
        for (int j = 0; j < 4; ++j) {
#pragma unroll
            for (int r = 0; r < 4; ++r) {
                const int row = rb + 16 * i + r;
                const int col = cb + 16 * j;
                const size_t idx = (size_t)row * Nn + col;
                float v = acc[i][j][r];
                if constexpr (MODE == 0) {
                    Cf[idx] = v;
                } else if constexpr (MODE == 1) {
                    if constexpr (RESBF) v += bf16_to_f32(resb[idx]);
                    else                 v += res[idx];
                    if (bias) v += bias[col];
                    if constexpr (OUTBF) Cb[idx] = f32_to_bf16(v);
                    else                 Cf[idx] = v;
                } else if constexpr (MODE == 2) {
                    v = gelu_exact(v + bias[col]);
                    Cb[idx] = f32_to_bf16(v);
                }
            }
        }
    }
}

// ------------------------------------------------------- flash attention
// R9-proven config: swapped-operand 32x32 MFMA, 2-batch fused (bias staged
// once, shared), all streams via glds into a full double buffer (64KB ->
// 2 blocks/CU), counted vmcnt(8)+barrier. Max-free softmax, 4-way k-split.
// grid (16 qblk, 12 h, 4 ks), block 256.
__global__ __launch_bounds__(256, 2)
void attn_kernel(const u16t* __restrict__ Q, const u16t* __restrict__ K,
                 const u16t* __restrict__ VT, const float* __restrict__ bias,
                 u16t* __restrict__ Opart, float* __restrict__ Lpart)
{
    const int SEQ = 2048;
    const int h = blockIdx.y;
    const int ks = blockIdx.z;
    const int t = threadIdx.x;
    const int w = t >> 6, lane = t & 63;
    const int l32 = lane & 31, hi = lane >> 5;
    const int q = blockIdx.x * 128 + w * 32 + l32;
    const int bh0 = h, bh1 = 12 + h;

    // per 32KB buffer: [0,16K) bias [128q][128B=32k f32] swz row&7
    //   [16K) K0 [32k][128B] swz row&7 | [20K) K1 | [24K) V0 [64d][64B]
    //   swz (row>>1)&3 | [28K) V1.  Two buffers (64KB total).
    __shared__ __align__(16) char smem[65536];

    const u16t* qp0 = Q + ((size_t)bh0 * SEQ + q) * 64 + 8 * hi;
    const u16t* qp1 = Q + ((size_t)bh1 * SEQ + q) * 64 + 8 * hi;
    bf16x8 qf0[4], qf1[4];
#pragma unroll
    for (int dseg = 0; dseg < 4; ++dseg) {
        qf0[dseg] = *reinterpret_cast<const bf16x8*>(qp0 + dseg * 16);
        qf1[dseg] = *reinterpret_cast<const bf16x8*>(qp1 + dseg * 16);
    }

    const char* kg0 = (const char*)K + (size_t)bh0 * SEQ * 128;    // 128B rows
    const char* kg1 = (const char*)K + (size_t)bh1 * SEQ * 128;
    const char* vg0 = (const char*)VT + (size_t)bh0 * 64 * 4096;   // 4KB rows
    const char* vg1 = (const char*)VT + (size_t)bh1 * 64 * 4096;
    const char* bg = (const char*)bias +
                     ((size_t)h * SEQ + blockIdx.x * 128) * 8192;  // 8KB rows

    const int srow8 = lane >> 3;                        // 0..7
    const int sslotK = ((lane & 7) ^ srow8) * 16;       // 128B-row swizzle
    const int vrow  = w * 16 + (lane >> 2);             // 0..63
    const int sslotV = ((lane & 3) ^ ((vrow >> 1) & 3)) * 16;

    auto stage_all = [&](int bb, int k0) {              // 8 glds per wave
#pragma unroll
        for (int i = 0; i < 4; ++i) {
            const int row = 32 * w + 8 * i + srow8;
            glds16(bg + (size_t)row * 8192 + (size_t)k0 * 4 + sslotK,
                   smem + bb + 4096 * w + i * 1024);
        }
        glds16(kg0 + (size_t)(k0 + 8 * w + srow8) * 128 + sslotK,
               smem + bb + 16384 + w * 1024);
        glds16(kg1 + (size_t)(k0 + 8 * w + srow8) * 128 + sslotK,
               smem + bb + 20480 + w * 1024);
        glds16(vg0 + (size_t)vrow * 4096 + (size_t)k0 * 2 + sslotV,
               smem + bb + 24576 + w * 1024);
        glds16(vg1 + (size_t)vrow * 4096 + (size_t)k0 * 2 + sslotV,
               smem + bb + 28672 + w * 1024);
    };

    const int rsw = l32 & 7;
    int boff[4], koff[4];
#pragma unroll
    for (int g = 0; g < 4; ++g)
        boff[g] = (32 * w + l32) * 128 + ((((g << 1) + hi) ^ rsw) << 4);
#pragma unroll
    for (int dseg = 0; dseg < 4; ++dseg)
        koff[dseg] = l32 * 128 + ((((dseg << 1) + hi) ^ rsw) << 4);
    const int vr3 = (l32 >> 1) & 3;
    const int voff00 = l32 * 64 + ((hi ^ vr3) << 4);
    const int voff01 = l32 * 64 + (((2 + hi) ^ vr3) << 4);
    const int voff10 = voff00 + 32 * 64;
    const int voff11 = voff01 + 32 * 64;

    f32x16 o00, o01, o10, o11;   // [batch][d-half]
#pragma unroll
    for (int i = 0; i < 16; ++i) { o00[i] = 0.f; o01[i] = 0.f;
                                   o10[i] = 0.f; o11[i] = 0.f; }
    float lsum0 = 0.f, lsum1 = 0.f;

    auto batch_body = [&](const bf16x8 (&qf)[4], int kvbase, int vbase,
                          const f32x4 (&bv)[4], f32x16& oa, f32x16& ob,
                          float& lsum) {
        f32x16 st;
#pragma unroll
        for (int i = 0; i < 16; ++i) st[i] = 0.f;
#pragma unroll
        for (int dseg = 0; dseg < 4; ++dseg) {
            bf16x8 kf = *reinterpret_cast<const bf16x8*>(
                smem + kvbase + koff[dseg]);
            st = __builtin_amdgcn_mfma_f32_32x32x16_bf16(kf, qf[dseg], st, 0, 0, 0);
        }
        unsigned pk[8];
#pragma unroll
        for (int i2 = 0; i2 < 8; ++i2) {
            const int ia = 2 * i2, ib = 2 * i2 + 1;
            const float pa = __expf(st[ia] * 0.125f + bv[ia >> 2][ia & 3]);
            const float pb = __expf(st[ib] * 0.125f + bv[ib >> 2][ib & 3]);
            lsum += pa + pb;
            pk[i2] = cvt_pk_bf16(pa, pb);
        }
        unsigned sx[8];
#pragma unroll
        for (int i2 = 0; i2 < 8; ++i2)
            sx[i2] = (unsigned)__shfl_xor((int)pk[i2], 32);
        union { unsigned u[4]; bf16x8 v; } B0, B1;
        B0.u[0] = hi ? sx[2] : pk[0];
        B0.u[1] = hi ? sx[3] : pk[1];
        B0.u[2] = hi ? pk[2] : sx[0];
        B0.u[3] = hi ? pk[3] : sx[1];
        B1.u[0] = hi ? sx[6] : pk[4];
        B1.u[1] = hi ? sx[7] : pk[5];
        B1.u[2] = hi ? pk[6] : sx[4];
        B1.u[3] = hi ? pk[7] : sx[5];
        bf16x8 v00 = *reinterpret_cast<const bf16x8*>(smem + vbase + voff00);
        bf16x8 v01 = *reinterpret_cast<const bf16x8*>(smem + vbase + voff01);
        bf16x8 v10 = *reinterpret_cast<const bf16x8*>(smem + vbase + voff10);
        bf16x8 v11 = *reinterpret_cast<const bf16x8*>(smem + vbase + voff11);
        oa = __builtin_amdgcn_mfma_f32_32x32x16_bf16(v00, B0.v, oa, 0, 0, 0);
        oa = __builtin_amdgcn_mfma_f32_32x32x16_bf16(v01, B1.v, oa, 0, 0, 0);
        ob = __builtin_amdgcn_mfma_f32_32x32x16_bf16(v10, B0.v, ob, 0, 0, 0);
        ob = __builtin_amdgcn_mfma_f32_32x32x16_bf16(v11, B1.v, ob, 0, 0, 0);
    };

    const int kbeg = ks * 512;

    stage_all(0, kbeg);
    WAITN_BARRIER(0)

    int cur = 0;
    for (int i = 0; i < 16; ++i) {
        const int k0 = kbeg + 32 * i;
        if (i < 15) {
            stage_all(cur ^ 32768, k0 + 32);   // 8 glds: tile i+1
            WAITN_BARRIER(8)                   // retires tile i's 8 glds
        } else {
            WAITN_BARRIER(0)
        }
        {
            f32x4 bv[4];
#pragma unroll
            for (int g = 0; g < 4; ++g)
                bv[g] = *reinterpret_cast<const f32x4*>(smem + cur + boff[g]);
            batch_body(qf0, cur + 16384, cur + 24576, bv, o00, o01, lsum0);
            batch_body(qf1, cur + 20480, cur + 28672, bv, o10, o11, lsum1);
        }
        PLAIN_BARRIER()                        // all waves done reading buf cur
        cur ^= 32768;
    }

    lsum0 += __shfl_xor(lsum0, 32);
    lsum1 += __shfl_xor(lsum1, 32);

#pragma unroll
    for (int beta = 0; beta < 2; ++beta) {
        const int bh = beta ? bh1 : bh0;
        const f32x16& oa = beta ? o10 : o00;
        const f32x16& ob = beta ? o11 : o01;
        const float ls = beta ? lsum1 : lsum0;
        u16t* op = Opart + ((size_t)(ks * 24 + bh) * SEQ + q) * 64;
#pragma unroll
        for (int dh = 0; dh < 2; ++dh) {
            const f32x16& o = dh ? ob : oa;
#pragma unroll
            for (int g = 0; g < 4; ++g) {
                u32x2 pr;
                pr[0] = cvt_pk_bf16(o[4 * g], o[4 * g + 1]);
                pr[1] = cvt_pk_bf16(o[4 * g + 2], o[4 * g + 3]);
                *reinterpret_cast<u32x2*>(op + dh * 32 + 8 * g + 4 * hi) = pr;
            }
        }
        if (!hi)
            Lpart[(size_t)(ks * 24 + bh) * SEQ + q] = ls;
    }
}

// --------------------------------------------- combine k-split partials
// out[b,q,h*64+d] = sum_j O_j / sum_j l_j over 4 k-splits.
__global__ __launch_bounds__(256)
void attn_combine(const u16t* __restrict__ Opart,
                  const float* __restrict__ Lpart, u16t* __restrict__ out)
{
    const int idx = blockIdx.x * 256 + threadIdx.x;   // 0 .. 24*2048*8
    const int dg = idx & 7;
    const int q = (idx >> 3) & 2047;
    const int bh = idx >> 14;
    const int b = bh / 12, h = bh % 12;
    const size_t base = ((size_t)bh * 2048 + q) * 64 + dg * 8;
    const size_t stride = (size_t)24 * 2048 * 64;
    float acc[8] = {0.f, 0.f, 0.f, 0.f, 0.f, 0.f, 0.f, 0.f};
    float l = 0.f;
#pragma unroll
    for (int j = 0; j < 4; ++j) {
        const u32x4 a = *reinterpret_cast<const u32x4*>(Opart + base + j * stride);
#pragma unroll
        for (int m = 0; m < 4; ++m) {
            acc[2 * m]     += bf16_to_f32((u16t)(a[m] & 0xFFFF));
            acc[2 * m + 1] += bf16_to_f32((u16t)(a[m] >> 16));
        }
        l += Lpart[(size_t)j * 24 * 2048 + bh * 2048 + q];
    }
    const float inv = 1.0f / l;
    u32x4 r;
#pragma unroll
    for (int m = 0; m < 4; ++m)
        r[m] = cvt_pk_bf16(acc[2 * m] * inv, acc[2 * m + 1] * inv);
    *reinterpret_cast<u32x4*>(
        out + ((size_t)(b * 2048 + q)) * 768 + h * 64 + dg * 8) = r;
}

// ------------------------------------------------------------------ launch
extern "C" void kernel_launch(void* const* d_in, const int* in_sizes, int n_in,
                              void* d_out, int out_size, void* d_ws, size_t ws_size,
                              hipStream_t stream)
{
    const float* x    = (const float*)d_in[0];
    const float* Wqkv = (const float*)d_in[1];
    const float* Wout = (const float*)d_in[2];
    const float* g1   = (const float*)d_in[3];
    const float* be1  = (const float*)d_in[4];
    const float* g2   = (const float*)d_in[5];
    const float* be2  = (const float*)d_in[6];
    const float* W1   = (const float*)d_in[7];
    const float* b1   = (const float*)d_in[8];
    const float* W2   = (const float*)d_in[9];
    const float* b2   = (const float*)d_in[10];
    const float* ab   = (const float*)d_in[11];
    float* outp = (float*)d_out;

    char* ws = (char*)d_ws;
    size_t off = 0;
    auto alloc = [&](size_t bytes) -> char* {
        char* p = ws + off;
        off += (bytes + 255) & ~(size_t)255;
        return p;
    };

    u16t* WqkvT = (u16t*)alloc((size_t)2304 * 768 * 2);
    u16t* WoutT = (u16t*)alloc((size_t)768 * 768 * 2);
    u16t* W1T   = (u16t*)alloc((size_t)3072 * 768 * 2);
    u16t* W2T   = (u16t*)alloc((size_t)768 * 3072 * 2);
    u16t* h1    = (u16t*)alloc((size_t)4096 * 768 * 2);
    u16t* Qb    = (u16t*)alloc((size_t)24 * 2048 * 64 * 2);
    u16t* Kb    = (u16t*)alloc((size_t)24 * 2048 * 64 * 2);
    u16t* VTb   = (u16t*)alloc((size_t)24 * 64 * 2048 * 2);
    u16t* attnb = (u16t*)alloc((size_t)4096 * 768 * 2);
    u16t* x1b   = (u16t*)alloc((size_t)4096 * 768 * 2);
    u16t* h2    = (u16t*)alloc((size_t)4096 * 768 * 2);
    u16t* Opart = (u16t*)alloc((size_t)4 * 24 * 2048 * 64 * 2);
    float* Lpart = (float*)alloc((size_t)4 * 24 * 2048 * 4);
    u16t* act   = (u16t*)alloc((size_t)4096 * 3072 * 2);

    // weight prep (all four transposes in one launch)
    transpose_all<<<1728, 256, 0, stream>>>(Wqkv, Wout, W1, W2,
                                            WqkvT, WoutT, W1T, W2T);

    // attention block
    ln_kernel<false><<<4096, 192, 0, stream>>>(x, g1, be1, h1);
    gemm_kernel<3, 128, false, false, false><<<dim3(32, 18), 256, 0, stream>>>(
        h1, WqkvT, nullptr, nullptr, nullptr, nullptr, nullptr, Qb, Kb, VTb,
        4096, 2304, 768);
    attn_kernel<<<dim3(16, 12, 4), 256, 0, stream>>>(Qb, Kb, VTb, ab, Opart, Lpart);
    attn_combine<<<(24 * 2048 * 8) / 256, 256, 0, stream>>>(Opart, Lpart, attnb);
    // Wout: low-block-count -> DBUF; res = x (f32), out = x1b (bf16)
    gemm_kernel<1, 64, true, true, false><<<dim3(64, 6), 256, 0, stream>>>(
        attnb, WoutT, nullptr, x1b, nullptr, x, nullptr, nullptr, nullptr, nullptr,
        4096, 768, 768);

    // feed-forward block
    ln_kernel<true><<<4096, 192, 0, stream>>>(x1b, g2, be2, h2);
    gemm_kernel<2, 128, false, false, false><<<dim3(32, 24), 256, 0, stream>>>(
        h2, W1T, nullptr, act, b1, nullptr, nullptr, nullptr, nullptr, nullptr,
        4096, 3072, 768);
    // FF2: low-block-count -> DBUF; res = x1b (bf16), out = outp (f32)
    gemm_kernel<1, 64, true, false, true><<<dim3(64, 6), 256, 0, stream>>>(
        act, W2T, outp, nullptr, b2, nullptr, x1b, nullptr, nullptr, nullptr,
        4096, 768, 3072);
}